// Round 1
// baseline (393.181 us; speedup 1.0000x reference)
//
#include <hip/hip_runtime.h>
#include <stdint.h>
#include <stddef.h>

typedef __attribute__((ext_vector_type(4))) float f32x4;
typedef __attribute__((ext_vector_type(4))) int   i32x4;

constexpr int B = 4, P = 48000, C = 64, NY = 496, NX = 432, CMAP = 16;
constexpr int CT  = C + CMAP;            // 80 output channels
constexpr int X4  = NX / 4;              // 108 float4 groups per full row
constexpr int CQ  = C / 4;               // 16 channel quads
constexpr int GV2 = B * CQ * NY * X4;    // 3,428,352 threads (vox path)
constexpr int NBV = GV2 / 256;           // 13,392 vox blocks (exact)
constexpr int XH  = NX / 2;              // 216: half-row for map LDS tile
constexpr int XH4 = XH / 4;              // 54
constexpr int NBM = B * NY * 2;          // 3,968 map blocks (half-rows)
constexpr size_t PL = (size_t)NY * NX;   // 214,272 channel-plane stride
// Zero kernel: each block writes 16 KB contiguous (256 thr x 4 x 16B).
constexpr int ZB  = (C * (int)PL * 4) / 16384;   // 3,348 blocks per batch region
constexpr int NBZ = B * ZB;                      // 13,392

// Pass A: build inverse map cell -> point id (cells unique by construction)
__global__ void scatter_inv_kernel(const int* __restrict__ coords,
                                   int* __restrict__ inv) {
    int p = blockIdx.x * blockDim.x + threadIdx.x;
    if (p >= P) return;
    const int4 cd = ((const int4*)coords)[p];     // (b, 0, y, x)
    inv[(cd.x * NY + cd.z) * NX + cd.w] = p;
}

// Pass B: stream zeros over the 4 contiguous vox regions (ch 0..63 per batch).
// Fill-engine-shaped: 4 back-to-back 1KB-coalesced NT dwordx4 stores per wave.
__global__ void __launch_bounds__(256) zero_vox4_kernel(float* __restrict__ out) {
    const int blk = blockIdx.x;
    const int b   = blk / ZB;
    const int rb  = blk - b * ZB;
    float* base = out + (size_t)b * CT * PL + (size_t)rb * 4096
                      + (size_t)threadIdx.x * 4;
    #pragma unroll
    for (int k = 0; k < 4; ++k)
        __builtin_nontemporal_store((f32x4)0.f, (f32x4*)(base + k * 1024));
}

// Pass C: sparse vox scatter. One thread = one (b,cq,y,x4) group.
// 79% of groups are fully empty -> exit before any store (region pre-zeroed).
// Partially-occupied groups store the full f32x4 (zeros for empty lanes are
// the correct value). Gather = one f32x4/pid + 4x4 register transpose.
__global__ void __launch_bounds__(256) vox_sparse_kernel(
        const float* __restrict__ vox, const int* __restrict__ inv,
        float* __restrict__ out) {
    int g = blockIdx.x * 256 + threadIdx.x;       // < GV2, exact
    int x4   = g % X4;
    int rest = g / X4;
    int y   = rest % NY;
    int bcq = rest / NY;                          // b*16 + cq
    int cq  = bcq & (CQ - 1);
    int b   = bcq >> 4;
    int c0  = cq * 4;

    i32x4 p4 = ((const i32x4*)inv)[(b * NY + y) * X4 + x4];
    // pids -1 (empty) or >=0; AND keeps sign bit only if ALL empty (~79%)
    if ((p4.x & p4.y & p4.z & p4.w) < 0) return;

    f32x4 r0 = (f32x4)0.f, r1 = (f32x4)0.f, r2 = (f32x4)0.f, r3 = (f32x4)0.f;
    const f32x4* vox4 = (const f32x4*)vox;        // vox row = 16 f32x4
    if (p4.x >= 0) r0 = vox4[(size_t)p4.x * CQ + cq];
    if (p4.y >= 0) r1 = vox4[(size_t)p4.y * CQ + cq];
    if (p4.z >= 0) r2 = vox4[(size_t)p4.z * CQ + cq];
    if (p4.w >= 0) r3 = vox4[(size_t)p4.w * CQ + cq];

    float* ob = out + (((size_t)b * CT + c0) * NY + y) * NX + x4 * 4;
    f32x4 s;
    s.x = r0.x; s.y = r1.x; s.z = r2.x; s.w = r3.x;
    __builtin_nontemporal_store(s, (f32x4*)(ob));
    s.x = r0.y; s.y = r1.y; s.z = r2.y; s.w = r3.y;
    __builtin_nontemporal_store(s, (f32x4*)(ob + PL));
    s.x = r0.z; s.y = r1.z; s.z = r2.z; s.w = r3.z;
    __builtin_nontemporal_store(s, (f32x4*)(ob + 2 * PL));
    s.x = r0.w; s.y = r1.w; s.z = r2.w; s.w = r3.w;
    __builtin_nontemporal_store(s, (f32x4*)(ob + 3 * PL));
}

// Pass D: map transpose (LDS half-row tiles, fetch-once).
__global__ void __launch_bounds__(256) map_half_kernel(
        const float* __restrict__ map, float* __restrict__ out) {
    __shared__ __align__(16) float m_s[CMAP][XH];   // 13.8 KB

    const int blk = blockIdx.x;
    const int tid = threadIdx.x;
    const int half = blk & 1;
    const int by   = blk >> 1;
    const int b    = by / NY;
    const int y    = by - b * NY;
    const int x0   = half * XH;

    const f32x4* map4 = (const f32x4*)map;
    for (int i = tid; i < XH * 4; i += 256) {     // 864 quad-loads
        int xh = i >> 2, q = i & 3;
        f32x4 mv = map4[((size_t)(b * NX + x0 + xh) * NY + y) * 4 + q];
        m_s[q * 4 + 0][xh] = mv.x;
        m_s[q * 4 + 1][xh] = mv.y;
        m_s[q * 4 + 2][xh] = mv.z;
        m_s[q * 4 + 3][xh] = mv.w;
    }
    __syncthreads();

    const size_t out_base = ((size_t)b * CT + C) * PL + (size_t)y * NX + x0;
    for (int idx = tid; idx < CMAP * XH4; idx += 256) {   // 864 stores
        int cm = idx / XH4;
        int x4 = idx - cm * XH4;
        f32x4 v = *(const f32x4*)&m_s[cm][x4 * 4];        // ds_read_b128
        __builtin_nontemporal_store(v,
            (f32x4*)(out + out_base + (size_t)cm * PL + x4 * 4));
    }
}

// Fallback path (no workspace): zero canvas region then direct scatter.
__global__ void zero_vox_region_kernel(float* __restrict__ out) {
    int g = blockIdx.x * 256 + threadIdx.x;
    if (g >= B * C * NY * X4) return;
    int x4   = g % X4;
    int rest = g / X4;
    int y  = rest % NY;
    int bc = rest / NY;
    int c  = bc & (C - 1);
    int b  = bc >> 6;
    *(f32x4*)(out + (((size_t)b * CT + c) * NY + y) * NX + x4 * 4) = (f32x4)0.f;
}

__global__ void scatter_direct_kernel(const float* __restrict__ vox,
                                      const int* __restrict__ coords,
                                      float* __restrict__ out) {
    int p = blockIdx.x;
    int c = threadIdx.x;  // 0..63
    const int4 cd = ((const int4*)coords)[p];
    out[(((size_t)cd.x * CT + c) * NY + cd.z) * NX + cd.w] = vox[(size_t)p * C + c];
}

__global__ void map_only_kernel(const float* __restrict__ map,
                                float* __restrict__ out) {
    int g = blockIdx.x * 256 + threadIdx.x;
    if (g >= B * CMAP * NY * NX) return;
    int x    = g % NX;
    int rest = g / NX;
    int y  = rest % NY;
    int bc = rest / NY;
    int cm = bc & (CMAP - 1);
    int b  = bc >> 4;
    out[((size_t)b * CT + C + cm) * PL + (size_t)y * NX + x] =
        map[((size_t)(b * NX + x) * NY + y) * CMAP + cm];
}

extern "C" void kernel_launch(void* const* d_in, const int* in_sizes, int n_in,
                              void* d_out, int out_size, void* d_ws, size_t ws_size,
                              hipStream_t stream) {
    const float* vox    = (const float*)d_in[0];   // (P, 64) float32
    const int*   coords = (const int*)d_in[1];     // (P, 4) int32
    const float* map    = (const float*)d_in[3];   // (B, NX, NY, CMAP) float32
    float* out = (float*)d_out;                    // (B, 80, NY, NX) float32

    const size_t inv_bytes = (size_t)B * NY * NX * sizeof(int);  // 3.43 MB
    int* inv = (ws_size >= inv_bytes) ? (int*)d_ws : nullptr;

    if (inv) {
        (void)hipMemsetAsync(inv, 0xFF, inv_bytes, stream);      // all -1
        scatter_inv_kernel<<<(P + 255) / 256, 256, 0, stream>>>(coords, inv);
        zero_vox4_kernel<<<NBZ, 256, 0, stream>>>(out);
        vox_sparse_kernel<<<NBV, 256, 0, stream>>>(vox, inv, out);
        map_half_kernel<<<NBM, 256, 0, stream>>>(map, out);
    } else {
        zero_vox_region_kernel<<<(B * C * NY * X4 + 255) / 256, 256, 0, stream>>>(out);
        scatter_direct_kernel<<<P, 64, 0, stream>>>(vox, coords, out);
        map_only_kernel<<<(B * CMAP * NY * NX + 255) / 256, 256, 0, stream>>>(map, out);
    }
}

// Round 2
// 340.770 us; speedup vs baseline: 1.1538x; 1.1538x over previous
//
#include <hip/hip_runtime.h>
#include <stdint.h>
#include <stddef.h>

typedef __attribute__((ext_vector_type(4))) float f32x4;
typedef __attribute__((ext_vector_type(4))) int   i32x4;

constexpr int B = 4, P = 48000, C = 64, NY = 496, NX = 432, CMAP = 16;
constexpr int CT  = C + CMAP;            // 80 output channels
constexpr int X4  = NX / 4;              // 108 float4 groups per full row
constexpr int CQ  = C / 4;               // 16 channel quads
constexpr int GV2 = B * CQ * NY * X4;    // 3,428,352 threads (vox path)
constexpr int NBV = GV2 / 256;           // 13,392 vox blocks (exact)
constexpr int XH  = NX / 2;              // 216: half-row for map LDS tile
constexpr int XH4 = XH / 4;              // 54
constexpr int NBM = B * NY * 2;          // 3,968 map blocks (half-rows)

// Pass A: build inverse map cell -> point id (cells unique by construction)
__global__ void scatter_inv_kernel(const int* __restrict__ coords,
                                   int* __restrict__ inv) {
    int p = blockIdx.x * blockDim.x + threadIdx.x;
    if (p >= P) return;
    const int4 cd = ((const int4*)coords)[p];     // (b, 0, y, x)
    inv[(cd.x * NY + cd.z) * NX + cd.w] = p;
}

// Fused fill (round-0 structure, PLAIN stores — single-variable A/B vs NT):
//   blocks [0,NBM): map transpose (LDS half-row tiles, fetch-once)
//   blocks [NBM,..): vox path — one thread = one (b,y,x4) group x 4 channels.
//     inv int4 read once per 4 stores; gather = one f32x4/pid + 4x4 register
//     transpose. Stores go through L2 (write-combine to full lines).
__global__ void __launch_bounds__(256) fused_fill_kernel(
        const float* __restrict__ vox, const float* __restrict__ map,
        const int* __restrict__ inv, float* __restrict__ out) {
    __shared__ __align__(16) float m_s[CMAP][XH];   // 13.8 KB

    const int blk = blockIdx.x;
    const int tid = threadIdx.x;

    if (blk < NBM) {
        // ---- map path: half-row (b, y, half) ----
        const int half = blk & 1;
        const int by   = blk >> 1;
        const int b    = by / NY;
        const int y    = by - b * NY;
        const int x0   = half * XH;

        const f32x4* map4 = (const f32x4*)map;
        for (int i = tid; i < XH * 4; i += 256) {     // 864 quad-loads
            int xh = i >> 2, q = i & 3;
            f32x4 mv = map4[((size_t)(b * NX + x0 + xh) * NY + y) * 4 + q];
            m_s[q * 4 + 0][xh] = mv.x;
            m_s[q * 4 + 1][xh] = mv.y;
            m_s[q * 4 + 2][xh] = mv.z;
            m_s[q * 4 + 3][xh] = mv.w;
        }
        __syncthreads();

        const size_t out_base = ((size_t)b * CT + C) * NY * NX
                              + (size_t)y * NX + x0;
        for (int idx = tid; idx < CMAP * XH4; idx += 256) {   // 864 stores
            int cm = idx / XH4;
            int x4 = idx - cm * XH4;
            f32x4 v = *(const f32x4*)&m_s[cm][x4 * 4];        // ds_read_b128
            *(f32x4*)(out + out_base + (size_t)cm * (NY * NX) + x4 * 4) = v;
        }
    } else {
        // ---- vox path ----
        int g = (blk - NBM) * 256 + tid;              // < GV2, exact
        int x4   = g % X4;
        int rest = g / X4;
        int y   = rest % NY;
        int bcq = rest / NY;                          // b*16 + cq
        int cq  = bcq & (CQ - 1);
        int b   = bcq >> 4;
        int c0  = cq * 4;

        i32x4 p4 = ((const i32x4*)inv)[(b * NY + y) * X4 + x4];

        f32x4 r0 = (f32x4)0.f, r1 = (f32x4)0.f, r2 = (f32x4)0.f, r3 = (f32x4)0.f;
        // pids -1 (empty) or >=0; AND keeps sign bit only if ALL empty (~79%)
        if ((p4.x & p4.y & p4.z & p4.w) >= 0) {
            const f32x4* vox4 = (const f32x4*)vox;    // vox row = 16 f32x4
            if (p4.x >= 0) r0 = vox4[(size_t)p4.x * CQ + cq];
            if (p4.y >= 0) r1 = vox4[(size_t)p4.y * CQ + cq];
            if (p4.z >= 0) r2 = vox4[(size_t)p4.z * CQ + cq];
            if (p4.w >= 0) r3 = vox4[(size_t)p4.w * CQ + cq];
        }

        float* ob = out + (((size_t)b * CT + c0) * NY + y) * NX + x4 * 4;
        const size_t PL = (size_t)NY * NX;            // channel-plane stride
        f32x4 s;
        s.x = r0.x; s.y = r1.x; s.z = r2.x; s.w = r3.x;
        *(f32x4*)(ob) = s;
        s.x = r0.y; s.y = r1.y; s.z = r2.y; s.w = r3.y;
        *(f32x4*)(ob + PL) = s;
        s.x = r0.z; s.y = r1.z; s.z = r2.z; s.w = r3.z;
        *(f32x4*)(ob + 2 * PL) = s;
        s.x = r0.w; s.y = r1.w; s.z = r2.w; s.w = r3.w;
        *(f32x4*)(ob + 3 * PL) = s;
    }
}

// Fallback path (no workspace): zero canvas region then direct scatter.
__global__ void zero_vox_region_kernel(float* __restrict__ out) {
    int g = blockIdx.x * 256 + threadIdx.x;
    if (g >= B * C * NY * X4) return;
    int x4   = g % X4;
    int rest = g / X4;
    int y  = rest % NY;
    int bc = rest / NY;
    int c  = bc & (C - 1);
    int b  = bc >> 6;
    *(f32x4*)(out + (((size_t)b * CT + c) * NY + y) * NX + x4 * 4) = (f32x4)0.f;
}

__global__ void scatter_direct_kernel(const float* __restrict__ vox,
                                      const int* __restrict__ coords,
                                      float* __restrict__ out) {
    int p = blockIdx.x;
    int c = threadIdx.x;  // 0..63
    const int4 cd = ((const int4*)coords)[p];
    out[(((size_t)cd.x * CT + c) * NY + cd.z) * NX + cd.w] = vox[(size_t)p * C + c];
}

__global__ void map_only_kernel(const float* __restrict__ map,
                                float* __restrict__ out) {
    int g = blockIdx.x * 256 + threadIdx.x;
    if (g >= B * CMAP * NY * NX) return;
    int x    = g % NX;
    int rest = g / NX;
    int y  = rest % NY;
    int bc = rest / NY;
    int cm = bc & (CMAP - 1);
    int b  = bc >> 4;
    out[((size_t)b * CT + C + cm) * NY * NX + (size_t)y * NX + x] =
        map[((size_t)(b * NX + x) * NY + y) * CMAP + cm];
}

extern "C" void kernel_launch(void* const* d_in, const int* in_sizes, int n_in,
                              void* d_out, int out_size, void* d_ws, size_t ws_size,
                              hipStream_t stream) {
    const float* vox    = (const float*)d_in[0];   // (P, 64) float32
    const int*   coords = (const int*)d_in[1];     // (P, 4) int32
    const float* map    = (const float*)d_in[3];   // (B, NX, NY, CMAP) float32
    float* out = (float*)d_out;                    // (B, 80, NY, NX) float32

    const size_t inv_bytes = (size_t)B * NY * NX * sizeof(int);  // 3.43 MB
    int* inv = (ws_size >= inv_bytes) ? (int*)d_ws : nullptr;

    if (inv) {
        (void)hipMemsetAsync(inv, 0xFF, inv_bytes, stream);      // all -1
        scatter_inv_kernel<<<(P + 255) / 256, 256, 0, stream>>>(coords, inv);
        fused_fill_kernel<<<NBM + NBV, 256, 0, stream>>>(vox, map, inv, out);
    } else {
        zero_vox_region_kernel<<<(B * C * NY * X4 + 255) / 256, 256, 0, stream>>>(out);
        scatter_direct_kernel<<<P, 64, 0, stream>>>(vox, coords, out);
        map_only_kernel<<<(B * CMAP * NY * NX + 255) / 256, 256, 0, stream>>>(map, out);
    }
}

// Round 3
// 336.987 us; speedup vs baseline: 1.1668x; 1.0112x over previous
//
#include <hip/hip_runtime.h>
#include <stdint.h>
#include <stddef.h>

typedef __attribute__((ext_vector_type(4))) float f32x4;
typedef __attribute__((ext_vector_type(4))) int   i32x4;

constexpr int B = 4, P = 48000, C = 64, NY = 496, NX = 432, CMAP = 16;
constexpr int CT  = C + CMAP;            // 80 output channels
constexpr int X4  = NX / 4;              // 108 float4 groups per full row
constexpr int CQ  = C / 4;               // 16 channel quads
constexpr int GV2 = B * CQ * NY * X4;    // 3,428,352 threads (vox path)
constexpr int NBV = GV2 / 256;           // 13,392 vox virtual blocks (exact)
constexpr int XH  = NX / 2;              // 216: half-row for map LDS tile
constexpr int XH4 = XH / 4;              // 54
constexpr int NBM = B * NY * 2;          // 3,968 map virtual blocks (half-rows)
constexpr int NVB = NBM + NBV;           // 17,360 virtual blocks
constexpr int GRID = 2048;               // persistent: 8 blocks/CU, 32 waves/CU

// Pass A: build inverse map cell -> point id (cells unique by construction)
__global__ void scatter_inv_kernel(const int* __restrict__ coords,
                                   int* __restrict__ inv) {
    int p = blockIdx.x * blockDim.x + threadIdx.x;
    if (p >= P) return;
    const int4 cd = ((const int4*)coords)[p];     // (b, 0, y, x)
    inv[(cd.x * NY + cd.z) * NX + cd.w] = p;
}

// Fused fill, PERSISTENT grid-stride version (single variable vs round-0):
// same per-virtual-block work, but 2048 long-lived blocks loop over the
// 17,360 virtual blocks (~8.5 iters). Each wave issues ~34 independent NT
// stores over its lifetime (vs 4 then exit) — deep store pipeline, loads of
// iter i+1 overlap stores of iter i, launch/drain amortized 8x.
__global__ void __launch_bounds__(256) fused_fill_kernel(
        const float* __restrict__ vox, const float* __restrict__ map,
        const int* __restrict__ inv, float* __restrict__ out) {
    __shared__ __align__(16) float m_s[CMAP][XH];   // 13.8 KB

    const int tid = threadIdx.x;
    const size_t PL = (size_t)NY * NX;              // channel-plane stride

    for (int vb = blockIdx.x; vb < NVB; vb += GRID) {
        if (vb < NBM) {
            // ---- map path: half-row (b, y, half) ----
            const int half = vb & 1;
            const int by   = vb >> 1;
            const int b    = by / NY;
            const int y    = by - b * NY;
            const int x0   = half * XH;

            const f32x4* map4 = (const f32x4*)map;
            for (int i = tid; i < XH * 4; i += 256) {     // 864 quad-loads
                int xh = i >> 2, q = i & 3;
                f32x4 mv = map4[((size_t)(b * NX + x0 + xh) * NY + y) * 4 + q];
                m_s[q * 4 + 0][xh] = mv.x;
                m_s[q * 4 + 1][xh] = mv.y;
                m_s[q * 4 + 2][xh] = mv.z;
                m_s[q * 4 + 3][xh] = mv.w;
            }
            __syncthreads();

            const size_t out_base = ((size_t)b * CT + C) * PL
                                  + (size_t)y * NX + x0;
            for (int idx = tid; idx < CMAP * XH4; idx += 256) {   // 864 stores
                int cm = idx / XH4;
                int x4 = idx - cm * XH4;
                f32x4 v = *(const f32x4*)&m_s[cm][x4 * 4];        // ds_read_b128
                __builtin_nontemporal_store(v,
                    (f32x4*)(out + out_base + (size_t)cm * PL + x4 * 4));
            }
            __syncthreads();   // m_s reused next loop iteration
        } else {
            // ---- vox path ----
            int g = (vb - NBM) * 256 + tid;               // < GV2, exact
            int x4   = g % X4;
            int rest = g / X4;
            int y   = rest % NY;
            int bcq = rest / NY;                          // b*16 + cq
            int cq  = bcq & (CQ - 1);
            int b   = bcq >> 4;
            int c0  = cq * 4;

            i32x4 p4 = ((const i32x4*)inv)[(b * NY + y) * X4 + x4];

            f32x4 r0 = (f32x4)0.f, r1 = (f32x4)0.f, r2 = (f32x4)0.f, r3 = (f32x4)0.f;
            // pids -1 (empty) or >=0; AND keeps sign bit only if ALL empty (~79%)
            if ((p4.x & p4.y & p4.z & p4.w) >= 0) {
                const f32x4* vox4 = (const f32x4*)vox;    // vox row = 16 f32x4
                if (p4.x >= 0) r0 = vox4[(size_t)p4.x * CQ + cq];
                if (p4.y >= 0) r1 = vox4[(size_t)p4.y * CQ + cq];
                if (p4.z >= 0) r2 = vox4[(size_t)p4.z * CQ + cq];
                if (p4.w >= 0) r3 = vox4[(size_t)p4.w * CQ + cq];
            }

            float* ob = out + (((size_t)b * CT + c0) * NY + y) * NX + x4 * 4;
            f32x4 s;
            s.x = r0.x; s.y = r1.x; s.z = r2.x; s.w = r3.x;
            __builtin_nontemporal_store(s, (f32x4*)(ob));
            s.x = r0.y; s.y = r1.y; s.z = r2.y; s.w = r3.y;
            __builtin_nontemporal_store(s, (f32x4*)(ob + PL));
            s.x = r0.z; s.y = r1.z; s.z = r2.z; s.w = r3.z;
            __builtin_nontemporal_store(s, (f32x4*)(ob + 2 * PL));
            s.x = r0.w; s.y = r1.w; s.z = r2.w; s.w = r3.w;
            __builtin_nontemporal_store(s, (f32x4*)(ob + 3 * PL));
        }
    }
}

// Fallback path (no workspace): zero canvas region then direct scatter.
__global__ void zero_vox_region_kernel(float* __restrict__ out) {
    int g = blockIdx.x * 256 + threadIdx.x;
    if (g >= B * C * NY * X4) return;
    int x4   = g % X4;
    int rest = g / X4;
    int y  = rest % NY;
    int bc = rest / NY;
    int c  = bc & (C - 1);
    int b  = bc >> 6;
    *(f32x4*)(out + (((size_t)b * CT + c) * NY + y) * NX + x4 * 4) = (f32x4)0.f;
}

__global__ void scatter_direct_kernel(const float* __restrict__ vox,
                                      const int* __restrict__ coords,
                                      float* __restrict__ out) {
    int p = blockIdx.x;
    int c = threadIdx.x;  // 0..63
    const int4 cd = ((const int4*)coords)[p];
    out[(((size_t)cd.x * CT + c) * NY + cd.z) * NX + cd.w] = vox[(size_t)p * C + c];
}

__global__ void map_only_kernel(const float* __restrict__ map,
                                float* __restrict__ out) {
    int g = blockIdx.x * 256 + threadIdx.x;
    if (g >= B * CMAP * NY * NX) return;
    int x    = g % NX;
    int rest = g / NX;
    int y  = rest % NY;
    int bc = rest / NY;
    int cm = bc & (CMAP - 1);
    int b  = bc >> 4;
    out[((size_t)b * CT + C + cm) * NY * NX + (size_t)y * NX + x] =
        map[((size_t)(b * NX + x) * NY + y) * CMAP + cm];
}

extern "C" void kernel_launch(void* const* d_in, const int* in_sizes, int n_in,
                              void* d_out, int out_size, void* d_ws, size_t ws_size,
                              hipStream_t stream) {
    const float* vox    = (const float*)d_in[0];   // (P, 64) float32
    const int*   coords = (const int*)d_in[1];     // (P, 4) int32
    const float* map    = (const float*)d_in[3];   // (B, NX, NY, CMAP) float32
    float* out = (float*)d_out;                    // (B, 80, NY, NX) float32

    const size_t inv_bytes = (size_t)B * NY * NX * sizeof(int);  // 3.43 MB
    int* inv = (ws_size >= inv_bytes) ? (int*)d_ws : nullptr;

    if (inv) {
        (void)hipMemsetAsync(inv, 0xFF, inv_bytes, stream);      // all -1
        scatter_inv_kernel<<<(P + 255) / 256, 256, 0, stream>>>(coords, inv);
        fused_fill_kernel<<<GRID, 256, 0, stream>>>(vox, map, inv, out);
    } else {
        zero_vox_region_kernel<<<(B * C * NY * X4 + 255) / 256, 256, 0, stream>>>(out);
        scatter_direct_kernel<<<P, 64, 0, stream>>>(vox, coords, out);
        map_only_kernel<<<(B * CMAP * NY * NX + 255) / 256, 256, 0, stream>>>(map, out);
    }
}